// Round 11
// baseline (44.970 us; speedup 1.0000x reference)
//
#include <hip/hip_runtime.h>

// B=8, C=12, Ny=Nx=512, 3x3 depthwise conv SAME pad=1, channel-reduced, + Rq + Dq.
// Round-11: round-10 plane-split structure + explicit 2-deep channel pipeline.
// Plane-split makes a channel 6 loads (24 VGPR), so a 2-buffer ping-pong peaks
// at ~77 live regs (vs r5/r7's fused 3-buffer ~200 -> spill). Trades ~30% TLP
// (32 -> ~20-24 waves/CU) for 2x per-wave MLP (6 -> 12 outstanding loads).
#define NY 512
#define NX 512
#define CC 12

__device__ __forceinline__ void row_conv(const float4& v0, const float4& v1,
                                         float w0, float w1, float w2, int lane,
                                         float4& a0, float4& a1)
{
    float l0 = __shfl_up(v1.w, 1);    // px 8i-1 from lane i-1
    if (lane == 0) l0 = 0.f;          // image left edge
    float r1 = __shfl_down(v0.x, 1);  // px 8i+8 from lane i+1
    if (lane == 63) r1 = 0.f;         // image right edge

    a0.x += w0*l0   + w1*v0.x + w2*v0.y;
    a0.y += w0*v0.x + w1*v0.y + w2*v0.z;
    a0.z += w0*v0.y + w1*v0.z + w2*v0.w;
    a0.w += w0*v0.z + w1*v0.w + w2*v1.x;
    a1.x += w0*v0.w + w1*v1.x + w2*v1.y;
    a1.y += w0*v1.x + w1*v1.y + w2*v1.z;
    a1.z += w0*v1.y + w1*v1.z + w2*v1.w;
    a1.w += w0*v1.z + w1*v1.w + w2*r1;
}

// 6 vector loads of channel C's 3 rows into named regs (assignment, not decl)
#define LOAD6(P, C)                                                \
    {                                                              \
        const float* pl_ = cbase + (size_t)(C) * PS;               \
        P##t0 = *(const float4*)(pl_ + off_t);                     \
        P##t1 = *(const float4*)(pl_ + off_t + 4);                 \
        P##m0 = *(const float4*)(pl_ + off_m);                     \
        P##m1 = *(const float4*)(pl_ + off_m + 4);                 \
        P##b0 = *(const float4*)(pl_ + off_b);                     \
        P##b1 = *(const float4*)(pl_ + off_b + 4);                 \
    }

// Convolve buffer P with channel C's weights; prefetch channel C+1 into Q first.
#define STEP(C, P, Q)                                                        \
    {                                                                        \
        if ((C) + 1 < CC) LOAD6(Q, (C) + 1)                                  \
        const float* f_ = filt + (C) * 9;                                    \
        const float w00 = f_[0] * m_top, w01 = f_[1] * m_top,                \
                    w02 = f_[2] * m_top;                                     \
        const float w10 = f_[3], w11 = f_[4], w12 = f_[5];                   \
        const float w20 = f_[6] * m_bot, w21 = f_[7] * m_bot,                \
                    w22 = f_[8] * m_bot;                                     \
        row_conv(P##t0, P##t1, w00, w01, w02, lane, a0, a1);                 \
        row_conv(P##m0, P##m1, w10, w11, w12, lane, a0, a1);                 \
        row_conv(P##b0, P##b1, w20, w21, w22, lane, a0, a1);                 \
    }

// Block: 256 threads = 4 waves: (y0,re),(y0,im),(y0+1,re),(y0+1,im).
// Grid (NY/2, B) = (256, 8) = 2048 blocks -> 8192 waves.
__global__ __launch_bounds__(256)
void momentum_kernel(const float* __restrict__ Rq_re, const float* __restrict__ Rq_im,
                     const float* __restrict__ Dq_re, const float* __restrict__ Dq_im,
                     const float* __restrict__ cache_re, const float* __restrict__ cache_im,
                     const float* __restrict__ filt, float* __restrict__ out)
{
    const int tid  = threadIdx.x;
    const int wave = tid >> 6;
    const int lane = tid & 63;

    // XCD swizzle: bid%8 = XCD k -> swz in [256k, 256(k+1)) -> batch k,
    // contiguous y pairs. 2048 % 8 == 0 -> bijective.
    const int bid = blockIdx.x + (int)(blockIdx.y * gridDim.x);
    const int swz = (bid & 7) * 256 + (bid >> 3);
    const int b   = swz >> 8;
    const int y   = (swz & 255) * 2 + (wave >> 1);
    const int p   = wave & 1;               // 0 = re, 1 = im

    const float* Rq    = p ? Rq_im    : Rq_re;
    const float* Dq    = p ? Dq_im    : Dq_re;
    const float* cache = p ? cache_im : cache_re;

    const int x0 = lane * 8;

    // y-halo: clamped row + 0/1 weight mask (wave-uniform, branch-free loads)
    const int   ym1   = (y > 0)      ? y - 1 : 0;
    const int   yp1   = (y < NY - 1) ? y + 1 : NY - 1;
    const float m_top = (y > 0)      ? 1.f : 0.f;
    const float m_bot = (y < NY - 1) ? 1.f : 0.f;

    const int off_t = ym1 * NX + x0;
    const int off_m = y   * NX + x0;
    const int off_b = yp1 * NX + x0;

    const size_t PS = (size_t)NY * NX;
    const float* cbase = cache + (size_t)b * CC * PS;

    // ---- pointwise: Rq + Dq ----
    float4 a0, a1;
    {
        const int base = (b * NY + y) * NX + x0;
        const float4 q0 = *(const float4*)(Rq + base);
        const float4 q1 = *(const float4*)(Rq + base + 4);
        const float4 d0 = *(const float4*)(Dq + base);
        const float4 d1 = *(const float4*)(Dq + base + 4);
        a0 = make_float4(q0.x + d0.x, q0.y + d0.y, q0.z + d0.z, q0.w + d0.w);
        a1 = make_float4(q1.x + d1.x, q1.y + d1.y, q1.z + d1.z, q1.w + d1.w);
    }

    // ---- pipelined channel loop: ping-pong buffers u/v, all-static names ----
    float4 ut0, ut1, um0, um1, ub0, ub1;
    float4 vt0, vt1, vm0, vm1, vb0, vb1;

    LOAD6(u, 0)                  // prologue

    STEP(0,  u, v)  STEP(1,  v, u)
    STEP(2,  u, v)  STEP(3,  v, u)
    STEP(4,  u, v)  STEP(5,  v, u)
    STEP(6,  u, v)  STEP(7,  v, u)
    STEP(8,  u, v)  STEP(9,  v, u)
    STEP(10, u, v)  STEP(11, v, u)

    // ---- store (B, 2, NY, NX) ----
    float* o = out + ((size_t)(b * 2 + p) * NY + y) * NX + x0;
    *(float4*)(o)     = a0;
    *(float4*)(o + 4) = a1;
}

extern "C" void kernel_launch(void* const* d_in, const int* in_sizes, int n_in,
                              void* d_out, int out_size, void* d_ws, size_t ws_size,
                              hipStream_t stream) {
    const float* Rq_re    = (const float*)d_in[0];
    const float* Rq_im    = (const float*)d_in[1];
    const float* Dq_re    = (const float*)d_in[2];
    const float* Dq_im    = (const float*)d_in[3];
    const float* cache_re = (const float*)d_in[4];
    const float* cache_im = (const float*)d_in[5];
    const float* filt     = (const float*)d_in[6];
    float* out = (float*)d_out;

    dim3 block(256);
    dim3 grid(NY / 2, 8);   // 2048 blocks; in-kernel swizzle maps XCD->batch
    momentum_kernel<<<grid, block, 0, stream>>>(Rq_re, Rq_im, Dq_re, Dq_im,
                                                cache_re, cache_im, filt, out);
}

// Round 12
// 44.129 us; speedup vs baseline: 1.0191x; 1.0191x over previous
//
#include <hip/hip_runtime.h>

// B=8, C=12, Ny=Nx=512, 3x3 depthwise conv SAME pad=1, channel-reduced, + Rq + Dq.
// FINAL (= round 10, session best: 44.0 us, ~5.7 TB/s effective vs 6.3 ceiling).
// One wave = one full 512-px row of ONE plane (re or im) -> 8192 waves = all
// wave slots. Rolled channel loop, natural VGPR allocation (40 regs, no cap),
// weight-masked y-halo (branch-free clamped loads), shuffle x-halo (no edge
// loads), bijective XCD swizzle (batch k's y-range stays on XCD k's L2).
// Probed and rejected: register pipelines (spill or TLP loss, r5-r7, r11),
// LDS global_load_lds pipeline (occupancy collapse, r8), fused re+im (r9).
#define NY 512
#define NX 512
#define CC 12

__device__ __forceinline__ void row_conv(const float4& v0, const float4& v1,
                                         float w0, float w1, float w2, int lane,
                                         float4& a0, float4& a1)
{
    float l0 = __shfl_up(v1.w, 1);    // px 8i-1 from lane i-1
    if (lane == 0) l0 = 0.f;          // image left edge
    float r1 = __shfl_down(v0.x, 1);  // px 8i+8 from lane i+1
    if (lane == 63) r1 = 0.f;         // image right edge

    a0.x += w0*l0   + w1*v0.x + w2*v0.y;
    a0.y += w0*v0.x + w1*v0.y + w2*v0.z;
    a0.z += w0*v0.y + w1*v0.z + w2*v0.w;
    a0.w += w0*v0.z + w1*v0.w + w2*v1.x;
    a1.x += w0*v0.w + w1*v1.x + w2*v1.y;
    a1.y += w0*v1.x + w1*v1.y + w2*v1.z;
    a1.z += w0*v1.y + w1*v1.z + w2*v1.w;
    a1.w += w0*v1.z + w1*v1.w + w2*r1;
}

// Block: 256 threads = 4 waves: (y0,re),(y0,im),(y0+1,re),(y0+1,im).
// Grid (NY/2, B) = (256, 8) = 2048 blocks -> 8192 waves = all wave slots.
__global__ __launch_bounds__(256)
void momentum_kernel(const float* __restrict__ Rq_re, const float* __restrict__ Rq_im,
                     const float* __restrict__ Dq_re, const float* __restrict__ Dq_im,
                     const float* __restrict__ cache_re, const float* __restrict__ cache_im,
                     const float* __restrict__ filt, float* __restrict__ out)
{
    const int tid  = threadIdx.x;
    const int wave = tid >> 6;
    const int lane = tid & 63;

    // XCD swizzle: bid%8 = XCD k -> swz in [256k, 256(k+1)) -> batch k,
    // contiguous y pairs. 2048 % 8 == 0 -> bijective.
    const int bid = blockIdx.x + (int)(blockIdx.y * gridDim.x);
    const int swz = (bid & 7) * 256 + (bid >> 3);
    const int b   = swz >> 8;
    const int y   = (swz & 255) * 2 + (wave >> 1);
    const int p   = wave & 1;               // 0 = re, 1 = im

    const float* Rq    = p ? Rq_im    : Rq_re;
    const float* Dq    = p ? Dq_im    : Dq_re;
    const float* cache = p ? cache_im : cache_re;

    const int x0 = lane * 8;

    // y-halo: clamped row + 0/1 weight mask (wave-uniform, branch-free loads)
    const int   ym1   = (y > 0)      ? y - 1 : 0;
    const int   yp1   = (y < NY - 1) ? y + 1 : NY - 1;
    const float m_top = (y > 0)      ? 1.f : 0.f;
    const float m_bot = (y < NY - 1) ? 1.f : 0.f;

    const int off_t = ym1 * NX + x0;
    const int off_m = y   * NX + x0;
    const int off_b = yp1 * NX + x0;

    // ---- pointwise: Rq + Dq (4 independent loads, one batch) ----
    float4 a0, a1;
    {
        const int base = (b * NY + y) * NX + x0;
        const float4 q0 = *(const float4*)(Rq + base);
        const float4 q1 = *(const float4*)(Rq + base + 4);
        const float4 d0 = *(const float4*)(Dq + base);
        const float4 d1 = *(const float4*)(Dq + base + 4);
        a0 = make_float4(q0.x + d0.x, q0.y + d0.y, q0.z + d0.z, q0.w + d0.w);
        a1 = make_float4(q1.x + d1.x, q1.y + d1.y, q1.z + d1.z, q1.w + d1.w);
    }

    // ---- channel-reduced depthwise 3x3: 6 unconditional loads per channel ----
    const size_t PS = (size_t)NY * NX;
    const float* cbase = cache + (size_t)b * CC * PS;

    for (int c = 0; c < CC; ++c) {
        const float* pl = cbase + (size_t)c * PS;
        const float4 t0 = *(const float4*)(pl + off_t);
        const float4 t1 = *(const float4*)(pl + off_t + 4);
        const float4 m0 = *(const float4*)(pl + off_m);
        const float4 m1 = *(const float4*)(pl + off_m + 4);
        const float4 b0 = *(const float4*)(pl + off_b);
        const float4 b1 = *(const float4*)(pl + off_b + 4);

        const float* f = filt + c * 9;           // uniform -> s_load path
        const float w00 = f[0] * m_top, w01 = f[1] * m_top, w02 = f[2] * m_top;
        const float w10 = f[3],         w11 = f[4],         w12 = f[5];
        const float w20 = f[6] * m_bot, w21 = f[7] * m_bot, w22 = f[8] * m_bot;

        row_conv(t0, t1, w00, w01, w02, lane, a0, a1);
        row_conv(m0, m1, w10, w11, w12, lane, a0, a1);
        row_conv(b0, b1, w20, w21, w22, lane, a0, a1);
    }

    // ---- store (B, 2, NY, NX) ----
    float* o = out + ((size_t)(b * 2 + p) * NY + y) * NX + x0;
    *(float4*)(o)     = a0;
    *(float4*)(o + 4) = a1;
}

extern "C" void kernel_launch(void* const* d_in, const int* in_sizes, int n_in,
                              void* d_out, int out_size, void* d_ws, size_t ws_size,
                              hipStream_t stream) {
    const float* Rq_re    = (const float*)d_in[0];
    const float* Rq_im    = (const float*)d_in[1];
    const float* Dq_re    = (const float*)d_in[2];
    const float* Dq_im    = (const float*)d_in[3];
    const float* cache_re = (const float*)d_in[4];
    const float* cache_im = (const float*)d_in[5];
    const float* filt     = (const float*)d_in[6];
    float* out = (float*)d_out;

    dim3 block(256);
    dim3 grid(NY / 2, 8);   // 2048 blocks; in-kernel swizzle maps XCD->batch
    momentum_kernel<<<grid, block, 0, stream>>>(Rq_re, Rq_im, Dq_re, Dq_im,
                                                cache_re, cache_im, filt, out);
}